// Round 3
// baseline (554.809 us; speedup 1.0000x reference)
//
#include <hip/hip_runtime.h>

// JKNet (6-layer GCN + JK concat) on MI355X — R10:
//   * FUSED agg_l + gemm_{l+1}: one kernel per layer boundary. Block aggregates
//     its 64 rows (4 waves x 16 rows, R9 gather loop), stores h into the LDS
//     X-tile, syncs, runs the MFMA gemm from LDS. 18 -> 13 launches; hidden
//     gemms no longer read hb from global; F5 fuses agg5+gemm_out (seg4 local).
//   * g double-buffered (gather source vs gemm dest must not alias).
//   * rest identical to R9 (fused prep, CSR build, bf16 JK segments).
// Layout facts (learn_hip m89): A[m=lane&15][k=quad*8+j], B[k][n=lane&15] (k=quad*8+j),
// D: col=lane&15, row=quad*4+reg.

typedef unsigned short ushortT;
typedef __attribute__((ext_vector_type(8))) short bf16x8;
typedef __attribute__((ext_vector_type(4))) float f32x4;

__device__ __forceinline__ ushortT f2b(float f) {
    union { float f; unsigned int u; } v;
    v.f = f;
    unsigned int lsb = (v.u >> 16) & 1u;
    v.u += 0x7fffu + lsb;  // RNE
    return (ushortT)(v.u >> 16);
}
__device__ __forceinline__ float b2f(ushortT u) {
    union { float f; unsigned int u; } v;
    v.u = ((unsigned int)u) << 16;
    return v.f;
}

// ---- fused prep: transpose+convert all weights, zero degi -----------------
__global__ void prep_kernel(const float* __restrict__ W1, const float* __restrict__ Wsl,
                            const float* __restrict__ Wout, ushortT* __restrict__ wt1,
                            ushortT* __restrict__ wts, ushortT* __restrict__ wto,
                            int* __restrict__ degi, int n) {
    const int SQ = 96 * 96;        // 9216
    const int T1 = 5 * SQ;         // 46080
    const int T2 = T1 + 480 * 64;  // 76800
    int i = blockIdx.x * blockDim.x + threadIdx.x;
    if (i < T1) {
        int l = i / SQ, j = i - l * SQ;
        int c = j / 96, k = j - c * 96;
        if (l == 0)
            wt1[j] = f2b(W1[k * 96 + c]);
        else
            wts[(size_t)(l - 1) * SQ + j] = f2b(Wsl[(size_t)(l - 1) * SQ + k * 96 + c]);
    } else if (i < T2) {
        int j = i - T1;
        int c = j / 480, k = j - c * 480;
        wto[j] = f2b(Wout[(size_t)k * 64 + c]);
    } else {
        int j = i - T2;
        if (j < n) degi[j] = 0;
    }
}

// ---- CSR build -------------------------------------------------------------
__global__ void count_kernel(const int* __restrict__ dst, int* __restrict__ degi, int E) {
    int e = blockIdx.x * blockDim.x + threadIdx.x;
    if (e < E) atomicAdd(&degi[dst[e]], 1);
}

__global__ void scan1(const int* __restrict__ degi, int* __restrict__ row_start,
                      int* __restrict__ partials, int n) {
    __shared__ int tmp[256];
    const int t = threadIdx.x;
    const int i = blockIdx.x * 256 + t;
    int val = (i < n) ? degi[i] : 0;
    tmp[t] = val;
    __syncthreads();
    for (int off = 1; off < 256; off <<= 1) {
        int v = (t >= off) ? tmp[t - off] : 0;
        __syncthreads();
        tmp[t] += v;
        __syncthreads();
    }
    if (i < n) row_start[i] = tmp[t] - val;
    if (t == 255) partials[blockIdx.x] = tmp[255];
}

__global__ void scan2(int* __restrict__ partials, int nb) {
    __shared__ int tmp[256];
    const int t = threadIdx.x;
    int val = (t < nb) ? partials[t] : 0;
    tmp[t] = val;
    __syncthreads();
    for (int off = 1; off < 256; off <<= 1) {
        int v = (t >= off) ? tmp[t - off] : 0;
        __syncthreads();
        tmp[t] += v;
        __syncthreads();
    }
    if (t < nb) partials[t] = tmp[t] - val;
}

__global__ void scan3(const int* __restrict__ degi, int* __restrict__ row_start,
                      const int* __restrict__ partials, float* __restrict__ dinv,
                      int n, int E) {
    const int i = blockIdx.x * 256 + threadIdx.x;
    if (i < n) {
        row_start[i] += partials[blockIdx.x];
        dinv[i] = rsqrtf((float)degi[i] + 1.0f);
    }
    if (i == 0) row_start[n] = E;
}

__global__ void fill_kernel(const int* __restrict__ src, const int* __restrict__ dst,
                            const int* __restrict__ row_start, int* __restrict__ degi,
                            int* __restrict__ col, int E) {
    int e = blockIdx.x * blockDim.x + threadIdx.x;
    if (e < E) {
        int d = dst[e];
        int pos = row_start[d] + atomicSub(&degi[d], 1) - 1;
        col[pos] = src[e];
    }
}

// ---- MFMA GEMM [n,96]x[96,96] -> g(bf16) = (X@W)*dinv[row] (layer 1 + fallback)
template <typename TIN>
__global__ __launch_bounds__(256) void gemm96_mfma(const TIN* __restrict__ X,
                                                   const ushortT* __restrict__ Wt, // [96][96] c-major
                                                   const float* __restrict__ dinv,
                                                   ushortT* __restrict__ g, int n) {
    __shared__ __attribute__((aligned(16))) ushortT Xl[64][104];
    __shared__ __attribute__((aligned(16))) ushortT Wtl[96][104];
    const int tid = threadIdx.x;
    const int wave = tid >> 6, lane = tid & 63;
    const int quad = lane >> 4, m = lane & 15;
    const int row_base = blockIdx.x * 64;
    for (int i = tid; i < 96 * 24; i += 256) {
        int r = i / 24, c4 = (i % 24) * 4;
        *(ushort4*)&Wtl[r][c4] = *(const ushort4*)&Wt[r * 96 + c4];
    }
    for (int i = tid; i < 64 * 24; i += 256) {
        int r = i / 24, c4 = (i % 24) * 4;
        int grow = min(row_base + r, n - 1);
        if constexpr (sizeof(TIN) == 4) {
            float4 v = *(const float4*)&X[(size_t)grow * 96 + c4];
            ushort4 o = {f2b(v.x), f2b(v.y), f2b(v.z), f2b(v.w)};
            *(ushort4*)&Xl[r][c4] = o;
        } else {
            *(ushort4*)&Xl[r][c4] = *(const ushort4*)&X[(size_t)grow * 96 + c4];
        }
    }
    __syncthreads();
    f32x4 acc[6] = {};
#pragma unroll
    for (int ks = 0; ks < 3; ++ks) {
        bf16x8 a = *(bf16x8*)&Xl[wave * 16 + m][ks * 32 + quad * 8];
#pragma unroll
        for (int ct = 0; ct < 6; ++ct) {
            bf16x8 b = *(bf16x8*)&Wtl[ct * 16 + m][ks * 32 + quad * 8];
            acc[ct] = __builtin_amdgcn_mfma_f32_16x16x32_bf16(a, b, acc[ct], 0, 0, 0);
        }
    }
    float di[4];
    int rows[4];
#pragma unroll
    for (int r = 0; r < 4; ++r) {
        rows[r] = row_base + wave * 16 + quad * 4 + r;
        di[r] = (rows[r] < n) ? dinv[rows[r]] : 0.f;
    }
#pragma unroll
    for (int ct = 0; ct < 6; ++ct) {
        int colx = ct * 16 + m;
#pragma unroll
        for (int r = 0; r < 4; ++r)
            if (rows[r] < n) g[(size_t)rows[r] * 96 + colx] = f2b(acc[ct][r] * di[r]);
    }
}

// ---- MFMA GEMM [n,480]x[480,64] (fallback only) ----------------------------
template <typename TIN>
__global__ __launch_bounds__(256) void gemm_out_mfma(const TIN* __restrict__ hcat,
                                                     const ushortT* __restrict__ Wt, // [64][480]
                                                     const float* __restrict__ dinv,
                                                     ushortT* __restrict__ g, int n) {
    __shared__ __attribute__((aligned(16))) ushortT Xl[64][104];
    __shared__ __attribute__((aligned(16))) ushortT Wtl[64][104];
    const int tid = threadIdx.x;
    const int wave = tid >> 6, lane = tid & 63;
    const int quad = lane >> 4, m = lane & 15;
    const int row_base = blockIdx.x * 64;
    f32x4 acc[4] = {};
    for (int seg = 0; seg < 5; ++seg) {
        const TIN* hl = hcat + (size_t)seg * (size_t)n * 96;
        __syncthreads();
        for (int i = tid; i < 64 * 24; i += 256) {
            int r = i / 24, c4 = (i % 24) * 4;
            *(ushort4*)&Wtl[r][c4] = *(const ushort4*)&Wt[r * 480 + seg * 96 + c4];
        }
        for (int i = tid; i < 64 * 24; i += 256) {
            int r = i / 24, c4 = (i % 24) * 4;
            int grow = min(row_base + r, n - 1);
            if constexpr (sizeof(TIN) == 4) {
                float4 v = *(const float4*)&hl[(size_t)grow * 96 + c4];
                ushort4 o = {f2b(v.x), f2b(v.y), f2b(v.z), f2b(v.w)};
                *(ushort4*)&Xl[r][c4] = o;
            } else {
                *(ushort4*)&Xl[r][c4] = *(const ushort4*)&hl[(size_t)grow * 96 + c4];
            }
        }
        __syncthreads();
#pragma unroll
        for (int ks = 0; ks < 3; ++ks) {
            bf16x8 a = *(bf16x8*)&Xl[wave * 16 + m][ks * 32 + quad * 8];
#pragma unroll
            for (int ct = 0; ct < 4; ++ct) {
                bf16x8 b = *(bf16x8*)&Wtl[ct * 16 + m][ks * 32 + quad * 8];
                acc[ct] = __builtin_amdgcn_mfma_f32_16x16x32_bf16(a, b, acc[ct], 0, 0, 0);
            }
        }
    }
    float di[4];
    int rows[4];
#pragma unroll
    for (int r = 0; r < 4; ++r) {
        rows[r] = row_base + wave * 16 + quad * 4 + r;
        di[r] = (rows[r] < n) ? dinv[rows[r]] : 0.f;
    }
#pragma unroll
    for (int ct = 0; ct < 4; ++ct) {
        int colx = ct * 16 + m;
#pragma unroll
        for (int r = 0; r < 4; ++r)
            if (rows[r] < n) g[(size_t)rows[r] * 64 + colx] = f2b(acc[ct][r] * di[r]);
    }
}

// ---- standalone CSR aggregate (final layer + fallback) ---------------------
template <int F, bool RELU, bool WRITE_BF16>
__global__ void agg_csr(const int* __restrict__ row_start, const int* __restrict__ col,
                        const ushortT* __restrict__ g, const float* __restrict__ dinv,
                        const float* __restrict__ b, float* __restrict__ out,
                        ushortT* __restrict__ hb, int n) {
    constexpr int NV = F / 4;
    const int lane = threadIdx.x & 63;
    const int half = lane >> 5;
    const int l32 = lane & 31;
    const int v = blockIdx.x * (blockDim.x >> 6) + (threadIdx.x >> 6);
    if (v >= n) return;
    const int e0 = row_start[v];
    const int e1 = row_start[v + 1];
    const bool act = (l32 < NV);
    const size_t fo = (size_t)l32 * 4;
    float a0 = 0.f, a1 = 0.f, a2 = 0.f, a3 = 0.f;
    float s0 = 0.f, s1 = 0.f, s2 = 0.f, s3 = 0.f;
    if (half == 0 && act) {  // self loop
        ushort4 s = *(const ushort4*)&g[(size_t)v * F + fo];
        a0 = b2f(s.x); a1 = b2f(s.y); a2 = b2f(s.z); a3 = b2f(s.w);
    }
    const int total = e1 - e0;
    const int cntH = (total - half + 1) >> 1;
    const int base = e0 + half;
    const int sb = half << 5;
    int done = 0;
    while (done < cntH) {
        const int kc = min(cntH - done, 32);
        int cv = 0;
        if (l32 < kc) cv = col[base + 2 * (done + l32)];
        int j = 0;
        for (; j + 8 <= kc; j += 8) {
            int c0 = __shfl(cv, sb + j + 0);
            int c1 = __shfl(cv, sb + j + 1);
            int c2 = __shfl(cv, sb + j + 2);
            int c3 = __shfl(cv, sb + j + 3);
            int c4 = __shfl(cv, sb + j + 4);
            int c5 = __shfl(cv, sb + j + 5);
            int c6 = __shfl(cv, sb + j + 6);
            int c7 = __shfl(cv, sb + j + 7);
            if (act) {
                ushort4 g0 = *(const ushort4*)&g[(size_t)c0 * F + fo];
                ushort4 g1 = *(const ushort4*)&g[(size_t)c1 * F + fo];
                ushort4 g2 = *(const ushort4*)&g[(size_t)c2 * F + fo];
                ushort4 g3 = *(const ushort4*)&g[(size_t)c3 * F + fo];
                ushort4 g4 = *(const ushort4*)&g[(size_t)c4 * F + fo];
                ushort4 g5 = *(const ushort4*)&g[(size_t)c5 * F + fo];
                ushort4 g6 = *(const ushort4*)&g[(size_t)c6 * F + fo];
                ushort4 g7 = *(const ushort4*)&g[(size_t)c7 * F + fo];
                a0 += (b2f(g0.x) + b2f(g1.x)) + (b2f(g2.x) + b2f(g3.x));
                a1 += (b2f(g0.y) + b2f(g1.y)) + (b2f(g2.y) + b2f(g3.y));
                a2 += (b2f(g0.z) + b2f(g1.z)) + (b2f(g2.z) + b2f(g3.z));
                a3 += (b2f(g0.w) + b2f(g1.w)) + (b2f(g2.w) + b2f(g3.w));
                s0 += (b2f(g4.x) + b2f(g5.x)) + (b2f(g6.x) + b2f(g7.x));
                s1 += (b2f(g4.y) + b2f(g5.y)) + (b2f(g6.y) + b2f(g7.y));
                s2 += (b2f(g4.z) + b2f(g5.z)) + (b2f(g6.z) + b2f(g7.z));
                s3 += (b2f(g4.w) + b2f(g5.w)) + (b2f(g6.w) + b2f(g7.w));
            }
        }
        if (j + 4 <= kc) {
            int c0 = __shfl(cv, sb + j + 0);
            int c1 = __shfl(cv, sb + j + 1);
            int c2 = __shfl(cv, sb + j + 2);
            int c3 = __shfl(cv, sb + j + 3);
            if (act) {
                ushort4 g0 = *(const ushort4*)&g[(size_t)c0 * F + fo];
                ushort4 g1 = *(const ushort4*)&g[(size_t)c1 * F + fo];
                ushort4 g2 = *(const ushort4*)&g[(size_t)c2 * F + fo];
                ushort4 g3 = *(const ushort4*)&g[(size_t)c3 * F + fo];
                a0 += b2f(g0.x) + b2f(g1.x);
                a1 += b2f(g0.y) + b2f(g1.y);
                a2 += b2f(g0.z) + b2f(g1.z);
                a3 += b2f(g0.w) + b2f(g1.w);
                s0 += b2f(g2.x) + b2f(g3.x);
                s1 += b2f(g2.y) + b2f(g3.y);
                s2 += b2f(g2.z) + b2f(g3.z);
                s3 += b2f(g2.w) + b2f(g3.w);
            }
            j += 4;
        }
        if (j + 2 <= kc) {
            int c0 = __shfl(cv, sb + j + 0);
            int c1 = __shfl(cv, sb + j + 1);
            if (act) {
                ushort4 g0 = *(const ushort4*)&g[(size_t)c0 * F + fo];
                ushort4 g1 = *(const ushort4*)&g[(size_t)c1 * F + fo];
                a0 += b2f(g0.x) + b2f(g1.x);
                a1 += b2f(g0.y) + b2f(g1.y);
                a2 += b2f(g0.z) + b2f(g1.z);
                a3 += b2f(g0.w) + b2f(g1.w);
            }
            j += 2;
        }
        if (j < kc) {
            int c0 = __shfl(cv, sb + j);
            if (act) {
                ushort4 g0 = *(const ushort4*)&g[(size_t)c0 * F + fo];
                a0 += b2f(g0.x); a1 += b2f(g0.y); a2 += b2f(g0.z); a3 += b2f(g0.w);
            }
        }
        done += kc;
    }
    a0 += s0; a1 += s1; a2 += s2; a3 += s3;
    a0 += __shfl_xor(a0, 32);
    a1 += __shfl_xor(a1, 32);
    a2 += __shfl_xor(a2, 32);
    a3 += __shfl_xor(a3, 32);
    if (half == 0 && act) {
        const float di = dinv[v];
        const float4 bv = *(const float4*)&b[l32 * 4];
        float4 r;
        r.x = a0 * di + bv.x;
        r.y = a1 * di + bv.y;
        r.z = a2 * di + bv.z;
        r.w = a3 * di + bv.w;
        if (RELU) {
            r.x = fmaxf(r.x, 0.f); r.y = fmaxf(r.y, 0.f);
            r.z = fmaxf(r.z, 0.f); r.w = fmaxf(r.w, 0.f);
        }
        *(float4*)&out[(size_t)v * F + l32 * 4] = r;
        if (WRITE_BF16) {
            ushort4 o = {f2b(r.x), f2b(r.y), f2b(r.z), f2b(r.w)};
            *(ushort4*)&hb[(size_t)v * F + l32 * 4] = o;
        }
    }
}

// ---- FUSED agg(layer l) + gemm(layer l+1) ----------------------------------
// Block owns 64 rows. 4 waves x 16 rows each: gather-aggregate from gin
// (prev layer's g, fully written at kernel boundary), write h fp32 (JK seg),
// hb bf16 (if !LAST), and the bf16 row into the LDS X-tile. Sync. Then MFMA
// gemm from LDS: !LAST -> [64,96]x[96,96] into gout[n][96];
// LAST -> [64,480]x[480,64] into gout[n][64] (seg4 = local Xl, segs 0-3 from hb_all).
// gin != gout (double-buffered) — blocks gather rows other blocks overwrite.
template <bool LAST>
__global__ __launch_bounds__(256, 4) void agg_gemm(
        const int* __restrict__ row_start, const int* __restrict__ col,
        const ushortT* __restrict__ gin, const float* __restrict__ dinv,
        const float* __restrict__ bias, float* __restrict__ hout,
        ushortT* __restrict__ hb_seg, const ushortT* __restrict__ Wt,
        const ushortT* __restrict__ hb_all, ushortT* __restrict__ gout, int n) {
    __shared__ __attribute__((aligned(16))) ushortT Xl[64][104];
    __shared__ __attribute__((aligned(16))) ushortT Wtl[96][104];
    const int tid = threadIdx.x;
    const int wave = tid >> 6, lane = tid & 63;
    const int half = lane >> 5, l32 = lane & 31;
    const int row_base = blockIdx.x * 64;

    // stage Wtl early — overlaps the agg phase (not read until after sync)
    if (!LAST) {
        for (int i = tid; i < 96 * 24; i += 256) {
            int r = i / 24, c4 = (i % 24) * 4;
            *(ushort4*)&Wtl[r][c4] = *(const ushort4*)&Wt[r * 96 + c4];
        }
    } else {
        for (int i = tid; i < 64 * 24; i += 256) {  // seg 4 slice
            int r = i / 24, c4 = (i % 24) * 4;
            *(ushort4*)&Wtl[r][c4] = *(const ushort4*)&Wt[r * 480 + 4 * 96 + c4];
        }
    }

    // ---- agg phase: wave handles rows row_base + wave*16 + rr --------------
    const bool act = (l32 < 24);
    const size_t fo = (size_t)l32 * 4;
    float4 bv = {0.f, 0.f, 0.f, 0.f};
    if (act) bv = *(const float4*)&bias[l32 * 4];
    const int sb = half << 5;

    for (int rr = 0; rr < 16; ++rr) {
        const int lr = wave * 16 + rr;
        const int v = row_base + lr;
        if (v < n) {
            const int e0 = row_start[v];
            const int e1 = row_start[v + 1];
            float a0 = 0.f, a1 = 0.f, a2 = 0.f, a3 = 0.f;
            float s0 = 0.f, s1 = 0.f, s2 = 0.f, s3 = 0.f;
            if (half == 0 && act) {  // self loop
                ushort4 s = *(const ushort4*)&gin[(size_t)v * 96 + fo];
                a0 = b2f(s.x); a1 = b2f(s.y); a2 = b2f(s.z); a3 = b2f(s.w);
            }
            const int total = e1 - e0;
            const int cntH = (total - half + 1) >> 1;
            const int base = e0 + half;
            int done = 0;
            while (done < cntH) {
                const int kc = min(cntH - done, 32);
                int cv = 0;
                if (l32 < kc) cv = col[base + 2 * (done + l32)];
                int j = 0;
                for (; j + 8 <= kc; j += 8) {
                    int c0 = __shfl(cv, sb + j + 0);
                    int c1 = __shfl(cv, sb + j + 1);
                    int c2 = __shfl(cv, sb + j + 2);
                    int c3 = __shfl(cv, sb + j + 3);
                    int c4 = __shfl(cv, sb + j + 4);
                    int c5 = __shfl(cv, sb + j + 5);
                    int c6 = __shfl(cv, sb + j + 6);
                    int c7 = __shfl(cv, sb + j + 7);
                    if (act) {
                        ushort4 g0 = *(const ushort4*)&gin[(size_t)c0 * 96 + fo];
                        ushort4 g1 = *(const ushort4*)&gin[(size_t)c1 * 96 + fo];
                        ushort4 g2 = *(const ushort4*)&gin[(size_t)c2 * 96 + fo];
                        ushort4 g3 = *(const ushort4*)&gin[(size_t)c3 * 96 + fo];
                        ushort4 g4 = *(const ushort4*)&gin[(size_t)c4 * 96 + fo];
                        ushort4 g5 = *(const ushort4*)&gin[(size_t)c5 * 96 + fo];
                        ushort4 g6 = *(const ushort4*)&gin[(size_t)c6 * 96 + fo];
                        ushort4 g7 = *(const ushort4*)&gin[(size_t)c7 * 96 + fo];
                        a0 += (b2f(g0.x) + b2f(g1.x)) + (b2f(g2.x) + b2f(g3.x));
                        a1 += (b2f(g0.y) + b2f(g1.y)) + (b2f(g2.y) + b2f(g3.y));
                        a2 += (b2f(g0.z) + b2f(g1.z)) + (b2f(g2.z) + b2f(g3.z));
                        a3 += (b2f(g0.w) + b2f(g1.w)) + (b2f(g2.w) + b2f(g3.w));
                        s0 += (b2f(g4.x) + b2f(g5.x)) + (b2f(g6.x) + b2f(g7.x));
                        s1 += (b2f(g4.y) + b2f(g5.y)) + (b2f(g6.y) + b2f(g7.y));
                        s2 += (b2f(g4.z) + b2f(g5.z)) + (b2f(g6.z) + b2f(g7.z));
                        s3 += (b2f(g4.w) + b2f(g5.w)) + (b2f(g6.w) + b2f(g7.w));
                    }
                }
                if (j + 4 <= kc) {
                    int c0 = __shfl(cv, sb + j + 0);
                    int c1 = __shfl(cv, sb + j + 1);
                    int c2 = __shfl(cv, sb + j + 2);
                    int c3 = __shfl(cv, sb + j + 3);
                    if (act) {
                        ushort4 g0 = *(const ushort4*)&gin[(size_t)c0 * 96 + fo];
                        ushort4 g1 = *(const ushort4*)&gin[(size_t)c1 * 96 + fo];
                        ushort4 g2 = *(const ushort4*)&gin[(size_t)c2 * 96 + fo];
                        ushort4 g3 = *(const ushort4*)&gin[(size_t)c3 * 96 + fo];
                        a0 += b2f(g0.x) + b2f(g1.x);
                        a1 += b2f(g0.y) + b2f(g1.y);
                        a2 += b2f(g0.z) + b2f(g1.z);
                        a3 += b2f(g0.w) + b2f(g1.w);
                        s0 += b2f(g2.x) + b2f(g3.x);
                        s1 += b2f(g2.y) + b2f(g3.y);
                        s2 += b2f(g2.z) + b2f(g3.z);
                        s3 += b2f(g2.w) + b2f(g3.w);
                    }
                    j += 4;
                }
                if (j + 2 <= kc) {
                    int c0 = __shfl(cv, sb + j + 0);
                    int c1 = __shfl(cv, sb + j + 1);
                    if (act) {
                        ushort4 g0 = *(const ushort4*)&gin[(size_t)c0 * 96 + fo];
                        ushort4 g1 = *(const ushort4*)&gin[(size_t)c1 * 96 + fo];
                        a0 += b2f(g0.x) + b2f(g1.x);
                        a1 += b2f(g0.y) + b2f(g1.y);
                        a2 += b2f(g0.z) + b2f(g1.z);
                        a3 += b2f(g0.w) + b2f(g1.w);
                    }
                    j += 2;
                }
                if (j < kc) {
                    int c0 = __shfl(cv, sb + j);
                    if (act) {
                        ushort4 g0 = *(const ushort4*)&gin[(size_t)c0 * 96 + fo];
                        a0 += b2f(g0.x); a1 += b2f(g0.y); a2 += b2f(g0.z); a3 += b2f(g0.w);
                    }
                }
                done += kc;
            }
            a0 += s0; a1 += s1; a2 += s2; a3 += s3;
            a0 += __shfl_xor(a0, 32);
            a1 += __shfl_xor(a1, 32);
            a2 += __shfl_xor(a2, 32);
            a3 += __shfl_xor(a3, 32);
            if (half == 0 && act) {
                const float di = dinv[v];
                float4 r;
                r.x = fmaxf(a0 * di + bv.x, 0.f);
                r.y = fmaxf(a1 * di + bv.y, 0.f);
                r.z = fmaxf(a2 * di + bv.z, 0.f);
                r.w = fmaxf(a3 * di + bv.w, 0.f);
                *(float4*)&hout[(size_t)v * 96 + fo] = r;
                ushort4 o = {f2b(r.x), f2b(r.y), f2b(r.z), f2b(r.w)};
                if (!LAST) *(ushort4*)&hb_seg[(size_t)v * 96 + fo] = o;
                *(ushort4*)&Xl[lr][l32 * 4] = o;
            }
        } else {
            if (half == 0 && act) {
                ushort4 z = {0, 0, 0, 0};
                *(ushort4*)&Xl[lr][l32 * 4] = z;
            }
        }
    }
    __syncthreads();

    // ---- gemm phase --------------------------------------------------------
    const int quad = lane >> 4, m = lane & 15;
    float di[4];
    int rows[4];
#pragma unroll
    for (int r = 0; r < 4; ++r) {
        rows[r] = row_base + wave * 16 + quad * 4 + r;
        di[r] = (rows[r] < n) ? dinv[rows[r]] : 0.f;
    }

    if (!LAST) {
        f32x4 acc[6] = {};
#pragma unroll
        for (int ks = 0; ks < 3; ++ks) {
            bf16x8 a = *(bf16x8*)&Xl[wave * 16 + m][ks * 32 + quad * 8];
#pragma unroll
            for (int ct = 0; ct < 6; ++ct) {
                bf16x8 b = *(bf16x8*)&Wtl[ct * 16 + m][ks * 32 + quad * 8];
                acc[ct] = __builtin_amdgcn_mfma_f32_16x16x32_bf16(a, b, acc[ct], 0, 0, 0);
            }
        }
#pragma unroll
        for (int ct = 0; ct < 6; ++ct) {
            int colx = ct * 16 + m;
#pragma unroll
            for (int r = 0; r < 4; ++r)
                if (rows[r] < n) gout[(size_t)rows[r] * 96 + colx] = f2b(acc[ct][r] * di[r]);
        }
    } else {
        f32x4 acc[4] = {};
        // seg 4 from local Xl (Wtl pre-staged with seg-4 slice)
#pragma unroll
        for (int ks = 0; ks < 3; ++ks) {
            bf16x8 a = *(bf16x8*)&Xl[wave * 16 + m][ks * 32 + quad * 8];
#pragma unroll
            for (int ct = 0; ct < 4; ++ct) {
                bf16x8 b = *(bf16x8*)&Wtl[ct * 16 + m][ks * 32 + quad * 8];
                acc[ct] = __builtin_amdgcn_mfma_f32_16x16x32_bf16(a, b, acc[ct], 0, 0, 0);
            }
        }
        // segs 0..3 from global hb
        for (int seg = 0; seg < 4; ++seg) {
            __syncthreads();
            for (int i = tid; i < 64 * 24; i += 256) {
                int r = i / 24, c4 = (i % 24) * 4;
                *(ushort4*)&Wtl[r][c4] = *(const ushort4*)&Wt[r * 480 + seg * 96 + c4];
            }
            const ushortT* hs = hb_all + (size_t)seg * (size_t)n * 96;
            for (int i = tid; i < 64 * 24; i += 256) {
                int r = i / 24, c4 = (i % 24) * 4;
                int grow = min(row_base + r, n - 1);
                *(ushort4*)&Xl[r][c4] = *(const ushort4*)&hs[(size_t)grow * 96 + c4];
            }
            __syncthreads();
#pragma unroll
            for (int ks = 0; ks < 3; ++ks) {
                bf16x8 a = *(bf16x8*)&Xl[wave * 16 + m][ks * 32 + quad * 8];
#pragma unroll
                for (int ct = 0; ct < 4; ++ct) {
                    bf16x8 b = *(bf16x8*)&Wtl[ct * 16 + m][ks * 32 + quad * 8];
                    acc[ct] = __builtin_amdgcn_mfma_f32_16x16x32_bf16(a, b, acc[ct], 0, 0, 0);
                }
            }
        }
#pragma unroll
        for (int ct = 0; ct < 4; ++ct) {
            int colx = ct * 16 + m;
#pragma unroll
            for (int r = 0; r < 4; ++r)
                if (rows[r] < n) gout[(size_t)rows[r] * 64 + colx] = f2b(acc[ct][r] * di[r]);
        }
    }
}

extern "C" void kernel_launch(void* const* d_in, const int* in_sizes, int n_in,
                              void* d_out, int out_size, void* d_ws, size_t ws_size,
                              hipStream_t stream) {
    const float* x    = (const float*)d_in[0];
    const int*   ei   = (const int*)d_in[1];
    const float* W1   = (const float*)d_in[4];
    const float* b1   = (const float*)d_in[5];
    const float* Wsl  = (const float*)d_in[6];
    const float* bsl  = (const float*)d_in[7];
    const float* Wout = (const float*)d_in[8];
    const float* bout = (const float*)d_in[9];

    const int n = in_sizes[0] / 96;  // 50000
    const int E = in_sizes[1] / 2;   // 800000
    const int* src = ei;
    const int* dst = ei + E;

    // ws: degi row_start partials col (int) | dinv (f32) | gA gB (bf16 n*96 each)
    //     | hball (bf16, 5*n*96 or n*96) | wt1 wts wto (bf16)
    char* p = (char*)d_ws;
    int*     degi      = (int*)p;              p += (size_t)n * 4;
    int*     row_start = (int*)p;              p += (size_t)(n + 1) * 4;
    int*     partials  = (int*)p;              p += 256 * 4;
    int*     col       = (int*)p;              p += (size_t)E * 4;
    float*   dinv      = (float*)p;            p += (size_t)n * 4;
    ushortT* gA        = (ushortT*)p;          p += (size_t)n * 96 * 2;
    ushortT* gB        = (ushortT*)p;          p += (size_t)n * 96 * 2;
    ushortT* hball     = (ushortT*)p;
    const size_t wbytes = (size_t)(5 * 9216 + 30720) * 2;
    const size_t fixed  = (size_t)(p - (char*)d_ws);
    const bool   big    = (fixed + (size_t)5 * n * 96 * 2 + wbytes) <= ws_size;
    const size_t hbsz   = big ? (size_t)5 * n * 96 : (size_t)n * 96;
    p += hbsz * 2;
    ushortT* wt1 = (ushortT*)p;
    ushortT* wts = wt1 + 9216;
    ushortT* wto = wts + 4 * 9216;

    float* out  = (float*)d_out;          // [n,64]
    float* hseg = out + (size_t)n * 64;   // h1 base; 5 segments of n*96 fp32

    const int nthr = 256;
    const int gE   = (E + nthr - 1) / nthr;
    const int gAgg = (n + 3) / 4;
    const int gT64 = (n + 63) / 64;
    const int nb   = (n + 255) / 256;

    // fused prep: weights + degi zero
    const int prep_items = 76800 + n;
    prep_kernel<<<(prep_items + 255) / 256, 256, 0, stream>>>(W1, Wsl, Wout, wt1, wts,
                                                              wto, degi, n);

    // CSR build
    count_kernel<<<gE, nthr, 0, stream>>>(dst, degi, E);
    scan1<<<nb, 256, 0, stream>>>(degi, row_start, partials, n);
    scan2<<<1, 256, 0, stream>>>(partials, nb);
    scan3<<<nb, 256, 0, stream>>>(degi, row_start, partials, dinv, n, E);
    fill_kernel<<<gE, nthr, 0, stream>>>(src, dst, row_start, degi, col, E);

    if (big) {
        // layer 1 gemm: x(fp32) -> gA
        gemm96_mfma<float><<<gT64, 256, 0, stream>>>(x, wt1, dinv, gA, n);
        // F1..F4: agg layer i (gin) + gemm layer i+1 (gout), alternating buffers
        ushortT* gbuf[2] = {gA, gB};
        for (int i = 0; i < 4; ++i) {
            ushortT* gin  = gbuf[i & 1];
            ushortT* gout = gbuf[(i & 1) ^ 1];
            const float* bias = (i == 0) ? b1 : (bsl + (size_t)(i - 1) * 96);
            agg_gemm<false><<<gT64, 256, 0, stream>>>(
                row_start, col, gin, dinv, bias, hseg + (size_t)i * n * 96,
                hball + (size_t)i * n * 96, wts + (size_t)i * 9216, nullptr,
                gout, n);
        }
        // F5: agg layer 5 + gemm_out (seg4 local, segs 0-3 from hball)
        agg_gemm<true><<<gT64, 256, 0, stream>>>(
            row_start, col, gbuf[0], dinv, bsl + 3 * 96, hseg + (size_t)4 * n * 96,
            nullptr, wto, hball, gbuf[1], n);
        // final aggregate on 64-wide g
        agg_csr<64, false, false><<<gAgg, nthr, 0, stream>>>(row_start, col, gbuf[1],
                                                             dinv, bout, out, nullptr, n);
    } else {
        // fallback: unfused path (single g buffer, fp32 JK read)
        gemm96_mfma<float><<<gT64, 256, 0, stream>>>(x, wt1, dinv, gA, n);
        agg_csr<96, true, true><<<gAgg, nthr, 0, stream>>>(row_start, col, gA, dinv, b1,
                                                           hseg, hball, n);
        for (int l = 0; l < 4; ++l) {
            float* hnext = hseg + (size_t)(l + 1) * (size_t)n * 96;
            gemm96_mfma<ushortT><<<gT64, 256, 0, stream>>>(hball, wts + (size_t)l * 9216,
                                                           dinv, gA, n);
            agg_csr<96, true, true><<<gAgg, nthr, 0, stream>>>(row_start, col, gA, dinv,
                                                               bsl + (size_t)l * 96,
                                                               hnext, hball, n);
        }
        gemm_out_mfma<float><<<gT64, 256, 0, stream>>>(hseg, wto, dinv, gA, n);
        agg_csr<64, false, false><<<gAgg, nthr, 0, stream>>>(row_start, col, gA, dinv,
                                                             bout, out, nullptr, n);
    }
}